// Round 2
// baseline (2199.656 us; speedup 1.0000x reference)
//
#include <hip/hip_runtime.h>
#include <math.h>

#define HIDDEN 4096
#define NEXP   128
#define TOPK   8
#define BT     32    // tokens per block
#define BK     32    // K tile
#define XS_STR 34    // padded row stride (doubles) for Xs   [BK][BT]
#define WS_STR 130   // padded row stride (doubles) for Ws   [BK][NEXP]

// One block: 32 tokens x 128 experts, fp64 accumulation (rank-exact vs f64 ref).
// Software-pipelined: global loads for tile k+1 issued into registers before
// the FMA loop over tile k, so HBM latency hides under the f64 FMA phase.
__global__ __launch_bounds__(256)
void router_kernel(const float* __restrict__ X,
                   const float* __restrict__ W,
                   const float* __restrict__ Bias,
                   float* __restrict__ Out,
                   int T)
{
    __shared__ double smem[BK * XS_STR + BK * WS_STR];  // 5248 doubles = 41984 B
    double* Xs = smem;                 // [k][token], stride XS_STR
    double* Ws = smem + BK * XS_STR;   // [k][expert], stride WS_STR

    const int tid = threadIdx.x;
    const int tokBase = blockIdx.x * BT;

    // staging assignments
    const int xr = tid >> 3;            // 0..31 : token row for X stage
    const int xc = (tid & 7) * 4;       // col group (4 floats)
    const int we = tid >> 1;            // 0..127 : expert row for W stage
    const int wc = (tid & 1) * 16;      // col base (16 floats)

    // compute assignments: 4 tokens x 4 experts per thread
    const int t0 = (tid & 7) * 4;
    const int e0 = (tid >> 3) * 4;

    double acc[4][4];
    #pragma unroll
    for (int i = 0; i < 4; i++)
        #pragma unroll
        for (int j = 0; j < 4; j++)
            acc[i][j] = 0.0;

    const float* xp = X + (size_t)(tokBase + xr) * HIDDEN + xc;
    const float* wp = W + (size_t)we * HIDDEN + wc;

    // staged registers (tile in flight)
    float4 xv, wv0, wv1, wv2, wv3;

    // ---- prologue: load + store tile 0 ----
    xv  = *(const float4*)(xp);
    wv0 = *(const float4*)(wp + 0);
    wv1 = *(const float4*)(wp + 4);
    wv2 = *(const float4*)(wp + 8);
    wv3 = *(const float4*)(wp + 12);
    {
        Xs[(xc + 0) * XS_STR + xr] = (double)xv.x;
        Xs[(xc + 1) * XS_STR + xr] = (double)xv.y;
        Xs[(xc + 2) * XS_STR + xr] = (double)xv.z;
        Xs[(xc + 3) * XS_STR + xr] = (double)xv.w;
        const float wf[16] = {wv0.x, wv0.y, wv0.z, wv0.w,
                              wv1.x, wv1.y, wv1.z, wv1.w,
                              wv2.x, wv2.y, wv2.z, wv2.w,
                              wv3.x, wv3.y, wv3.z, wv3.w};
        #pragma unroll
        for (int q = 0; q < 16; q++)
            Ws[(wc + q) * WS_STR + we] = (double)wf[q];
    }
    __syncthreads();

    const int NTILES = HIDDEN / BK;  // 128
    for (int tile = 0; tile < NTILES; ++tile) {
        const bool more = (tile + 1) < NTILES;
        // ---- issue next tile's global loads (latency hidden by FMA loop) ----
        if (more) {
            const int k0n = (tile + 1) * BK;
            xv  = *(const float4*)(xp + k0n);
            wv0 = *(const float4*)(wp + k0n + 0);
            wv1 = *(const float4*)(wp + k0n + 4);
            wv2 = *(const float4*)(wp + k0n + 8);
            wv3 = *(const float4*)(wp + k0n + 12);
        }

        // ---- FMA over current LDS tile: 16 f64 FMAs per k ----
        #pragma unroll
        for (int k = 0; k < BK; k++) {
            const double* xrow = Xs + k * XS_STR + t0;
            const double* wrow = Ws + k * WS_STR + e0;
            const double x0 = xrow[0], x1 = xrow[1], x2 = xrow[2], x3 = xrow[3];
            const double w0 = wrow[0], w1 = wrow[1], w2 = wrow[2], w3 = wrow[3];
            acc[0][0] = fma(x0, w0, acc[0][0]);
            acc[0][1] = fma(x0, w1, acc[0][1]);
            acc[0][2] = fma(x0, w2, acc[0][2]);
            acc[0][3] = fma(x0, w3, acc[0][3]);
            acc[1][0] = fma(x1, w0, acc[1][0]);
            acc[1][1] = fma(x1, w1, acc[1][1]);
            acc[1][2] = fma(x1, w2, acc[1][2]);
            acc[1][3] = fma(x1, w3, acc[1][3]);
            acc[2][0] = fma(x2, w0, acc[2][0]);
            acc[2][1] = fma(x2, w1, acc[2][1]);
            acc[2][2] = fma(x2, w2, acc[2][2]);
            acc[2][3] = fma(x2, w3, acc[2][3]);
            acc[3][0] = fma(x3, w0, acc[3][0]);
            acc[3][1] = fma(x3, w1, acc[3][1]);
            acc[3][2] = fma(x3, w2, acc[3][2]);
            acc[3][3] = fma(x3, w3, acc[3][3]);
        }
        __syncthreads();

        // ---- store staged registers into LDS for next tile ----
        if (more) {
            Xs[(xc + 0) * XS_STR + xr] = (double)xv.x;
            Xs[(xc + 1) * XS_STR + xr] = (double)xv.y;
            Xs[(xc + 2) * XS_STR + xr] = (double)xv.z;
            Xs[(xc + 3) * XS_STR + xr] = (double)xv.w;
            const float wf[16] = {wv0.x, wv0.y, wv0.z, wv0.w,
                                  wv1.x, wv1.y, wv1.z, wv1.w,
                                  wv2.x, wv2.y, wv2.z, wv2.w,
                                  wv3.x, wv3.y, wv3.z, wv3.w};
            #pragma unroll
            for (int q = 0; q < 16; q++)
                Ws[(wc + q) * WS_STR + we] = (double)wf[q];
        }
        __syncthreads();
    }

    // ---- epilogue: biased sigmoid scores into padded LDS ----
    double* S = smem;  // [BT][WS_STR] = 32*130 = 4160 doubles <= 5248, reuse
    #pragma unroll
    for (int i = 0; i < 4; i++) {
        #pragma unroll
        for (int j = 0; j < 4; j++) {
            const double l = acc[i][j];
            const double s = 1.0 / (1.0 + exp(-l)) + (double)Bias[e0 + j];
            S[(t0 + i) * WS_STR + (e0 + j)] = s;
        }
    }
    __syncthreads();

    // ---- top-8, one thread per token (stable: lowest index on ties) ----
    if (tid < BT) {
        double* row = S + tid * WS_STR;
        int    cidx[TOPK];
        double csc[TOPK];
        #pragma unroll
        for (int p = 0; p < TOPK; p++) {
            double best = -1e300;
            int bi = 0;
            for (int e = 0; e < NEXP; e++) {
                const double v = row[e];
                if (v > best) { best = v; bi = e; }
            }
            cidx[p] = bi;
            csc[p]  = best;
            row[bi] = -1e300;
        }
        double sum = 0.0;
        double wts[TOPK];
        #pragma unroll
        for (int p = 0; p < TOPK; p++) {
            const double sg = csc[p] - (double)Bias[cidx[p]];
            wts[p] = sg;
            sum += sg;
        }
        const double inv = 1.0 / (sum + 1e-20);
        const int tok = tokBase + tid;
        float* oi = Out + (size_t)tok * TOPK;
        float* ow = Out + (size_t)T * TOPK + (size_t)tok * TOPK;
        #pragma unroll
        for (int p = 0; p < TOPK; p++) {
            oi[p] = (float)cidx[p];
            ow[p] = (float)(wts[p] * inv);
        }
    }
}

extern "C" void kernel_launch(void* const* d_in, const int* in_sizes, int n_in,
                              void* d_out, int out_size, void* d_ws, size_t ws_size,
                              hipStream_t stream) {
    const float* X    = (const float*)d_in[0];
    const float* W    = (const float*)d_in[1];
    const float* Bias = (const float*)d_in[2];
    float* Out = (float*)d_out;
    const int T = in_sizes[0] / HIDDEN;

    dim3 grid((T + BT - 1) / BT);
    dim3 block(256);
    hipLaunchKernelGGL(router_kernel, grid, block, 0, stream, X, W, Bias, Out, T);
}

// Round 4
// 452.968 us; speedup vs baseline: 4.8561x; 4.8561x over previous
//
#include <hip/hip_runtime.h>
#include <math.h>

#define HIDDEN 4096
#define NEXP   128
#define TOPK   8
#define BT     32
#define CHUNK  64
#define NCHUNK (HIDDEN / CHUNK)   // 64
#define SSTR   132                // epilogue score row stride (doubles)
#define PLANE  (NEXP * CHUNK)     // 8192 bytes per (chunk,slice) W plane

typedef int v4i __attribute__((ext_vector_type(4)));

static __device__ __forceinline__ unsigned pack4(int a, int b, int c, int d) {
    return (unsigned)(a & 255) | ((unsigned)(b & 255) << 8) |
           ((unsigned)(c & 255) << 16) | ((unsigned)(d & 255) << 24);
}

// Balanced base-128 slicing: val = M * sum_i d_i * 2^(-6-7i), |d_i| <= 64.
// scale1 = 2^13 / M. All float steps exact (pow2 mul, rint, Sterbenz sub).
// 5-digit: residual <= M*2^-35.  4-digit: residual <= M*2^-28.
static __device__ __forceinline__ void slice5(float val, float scale1,
        int& d0, int& d1, int& d2, int& d3, int& d4) {
    float v = val * scale1;
    float f = __builtin_rintf(v);
    float r = v - f;                                 // exact
    int nh = (int)f;                                 // |nh| <= 2^13
    int nl = (int)__builtin_rintf(r * 2097152.0f);   // 2^21, |nl| <= 2^20
    d0 = (nh + 64) >> 7;  d1 = nh - (d0 << 7);
    d2 = (nl + 8192) >> 14;
    int r2 = nl - (d2 << 14);
    d3 = (r2 + 64) >> 7;  d4 = r2 - (d3 << 7);
}

static __device__ __forceinline__ void slice4(float val, float scale1,
        int& d0, int& d1, int& d2, int& d3) {
    float v = val * scale1;
    float f = __builtin_rintf(v);
    float r = v - f;
    int nh = (int)f;
    int nl = (int)__builtin_rintf(r * 16384.0f);     // 2^14, |nl| <= 2^13
    d0 = (nh + 64) >> 7;  d1 = nh - (d0 << 7);
    d2 = (nl + 64) >> 7;  d3 = nl - (d2 << 7);
}

// ---------------- W pre-slicing: [c][s][e][64] i8 planes (2.62 MB) ----------
__global__ __launch_bounds__(256)
void slice_w_kernel(const float* __restrict__ W, signed char* __restrict__ P)
{
    const int t  = blockIdx.x * 256 + threadIdx.x;   // 65536 threads
    const int e  = t >> 9;
    const int k0 = (t & 511) * 8;
    const float* src = W + (size_t)e * HIDDEN + k0;
    const float4 a = ((const float4*)src)[0];
    const float4 b = ((const float4*)src)[1];

    // M_w = 0.25 -> scale1 = 2^15
    int p00,p01,p02,p03,p04; slice5(a.x, 32768.0f, p00,p01,p02,p03,p04);
    int p10,p11,p12,p13,p14; slice5(a.y, 32768.0f, p10,p11,p12,p13,p14);
    int p20,p21,p22,p23,p24; slice5(a.z, 32768.0f, p20,p21,p22,p23,p24);
    int p30,p31,p32,p33,p34; slice5(a.w, 32768.0f, p30,p31,p32,p33,p34);
    int p40,p41,p42,p43,p44; slice5(b.x, 32768.0f, p40,p41,p42,p43,p44);
    int p50,p51,p52,p53,p54; slice5(b.y, 32768.0f, p50,p51,p52,p53,p54);
    int p60,p61,p62,p63,p64; slice5(b.z, 32768.0f, p60,p61,p62,p63,p64);
    int p70,p71,p72,p73,p74; slice5(b.w, 32768.0f, p70,p71,p72,p73,p74);

    const int c = k0 >> 6, kin = k0 & 63;
    signed char* base = P + ((size_t)(c * 5) * NEXP + e) * CHUNK + kin;
    uint2 v;
    v.x = pack4(p00,p10,p20,p30); v.y = pack4(p40,p50,p60,p70);
    *(uint2*)(base + 0 * PLANE) = v;
    v.x = pack4(p01,p11,p21,p31); v.y = pack4(p41,p51,p61,p71);
    *(uint2*)(base + 1 * PLANE) = v;
    v.x = pack4(p02,p12,p22,p32); v.y = pack4(p42,p52,p62,p72);
    *(uint2*)(base + 2 * PLANE) = v;
    v.x = pack4(p03,p13,p23,p33); v.y = pack4(p43,p53,p63,p73);
    *(uint2*)(base + 3 * PLANE) = v;
    v.x = pack4(p04,p14,p24,p34); v.y = pack4(p44,p54,p64,p74);
    *(uint2*)(base + 4 * PLANE) = v;
}

// X slicing (M_x = 8 -> scale1 = 2^10): 8 elems -> 4 slice planes of 8 bytes
static __device__ __forceinline__ void slice_store_x(char* dst, float4 xa, float4 xb)
{
    int a00,a01,a02,a03; slice4(xa.x, 1024.0f, a00,a01,a02,a03);
    int a10,a11,a12,a13; slice4(xa.y, 1024.0f, a10,a11,a12,a13);
    int a20,a21,a22,a23; slice4(xa.z, 1024.0f, a20,a21,a22,a23);
    int a30,a31,a32,a33; slice4(xa.w, 1024.0f, a30,a31,a32,a33);
    int a40,a41,a42,a43; slice4(xb.x, 1024.0f, a40,a41,a42,a43);
    int a50,a51,a52,a53; slice4(xb.y, 1024.0f, a50,a51,a52,a53);
    int a60,a61,a62,a63; slice4(xb.z, 1024.0f, a60,a61,a62,a63);
    int a70,a71,a72,a73; slice4(xb.w, 1024.0f, a70,a71,a72,a73);
    uint2 v;
    v.x = pack4(a00,a10,a20,a30); v.y = pack4(a40,a50,a60,a70);
    *(uint2*)(dst + 0 * 2048) = v;
    v.x = pack4(a01,a11,a21,a31); v.y = pack4(a41,a51,a61,a71);
    *(uint2*)(dst + 1 * 2048) = v;
    v.x = pack4(a02,a12,a22,a32); v.y = pack4(a42,a52,a62,a72);
    *(uint2*)(dst + 2 * 2048) = v;
    v.x = pack4(a03,a13,a23,a33); v.y = pack4(a43,a53,a63,a73);
    *(uint2*)(dst + 3 * 2048) = v;
}

// ---------------- main router kernel ---------------------------------------
__global__ __launch_bounds__(256, 2)
void router_kernel(const float* __restrict__ X,
                   const signed char* __restrict__ P,
                   const float* __restrict__ Bias,
                   float* __restrict__ Out, int T)
{
    __shared__ double S[BT * SSTR];   // 33792 B; first 16 KB doubles as A staging
    char* Ast = (char*)S;             // [buf 8192][slice 2048][unit 16]

    const int tid  = threadIdx.x;
    const int lane = tid & 63;
    const int wave = tid >> 6;
    const int tokBase = blockIdx.x * BT;

    // slicing job: token sm, k-run of 8
    const int sm  = tid & 31;
    const int sk8 = tid >> 5;
    int srow = tokBase + sm; if (srow >= T) srow = T - 1;
    const float* xptr = X + (size_t)srow * HIDDEN + sk8 * 8;
    const int su    = sm * 4 + (sk8 >> 1);                    // unit = m*4 + k16
    const int swoff = ((su ^ ((su >> 3) & 7)) << 4) + (sk8 & 1) * 8;

    // A-frag LDS read offsets (m = lane&15, k-quarter = lane>>4)
    const int ru0  = ((lane & 15)     ) * 4 + (lane >> 4);
    const int ru1  = ((lane & 15) + 16) * 4 + (lane >> 4);
    const int rph0 = (ru0 ^ ((ru0 >> 3) & 7)) << 4;
    const int rph1 = (ru1 ^ ((ru1 >> 3) & 7)) << 4;

    // B global offsets (n = lane&15, k-quarter = lane>>4): contiguous 1KB/wave
    const int eb0 = wave * 32 + (lane & 15);
    const int koff = (lane >> 4) * 16;
    const size_t boff0 = (size_t)eb0 * CHUNK + koff;
    const size_t boff1 = boff0 + (size_t)16 * CHUNK;

    v4i acc[2][2][5];
    #pragma unroll
    for (int tt = 0; tt < 2; tt++)
        #pragma unroll
        for (int et = 0; et < 2; et++)
            #pragma unroll
            for (int s = 0; s < 5; s++)
                acc[tt][et][s] = (v4i){0,0,0,0};

    float4 xa = ((const float4*)xptr)[0];
    float4 xb = ((const float4*)xptr)[1];
    slice_store_x(Ast + swoff, xa, xb);
    __syncthreads();

    for (int c = 0; c < NCHUNK; c++) {
        const int buf = (c & 1) * 8192;
        if (c + 1 < NCHUNK) {                        // prefetch next X
            const float* nx = xptr + (c + 1) * CHUNK;
            xa = ((const float4*)nx)[0];
            xb = ((const float4*)nx)[1];
        }
        const signed char* pc = P + (size_t)(c * 5) * PLANE;
        v4i bf[2][5];
        #pragma unroll
        for (int s = 0; s < 5; s++) {
            bf[0][s] = *(const v4i*)(pc + (size_t)s * PLANE + boff0);
            bf[1][s] = *(const v4i*)(pc + (size_t)s * PLANE + boff1);
        }
        #pragma unroll
        for (int tt = 0; tt < 2; tt++) {
            const char* ap = Ast + buf + (tt ? rph1 : rph0);
            const v4i a0 = *(const v4i*)(ap + 0 * 2048);
            const v4i a1 = *(const v4i*)(ap + 1 * 2048);
            const v4i a2 = *(const v4i*)(ap + 2 * 2048);
            const v4i a3 = *(const v4i*)(ap + 3 * 2048);
            #pragma unroll
            for (int et = 0; et < 2; et++) {
                acc[tt][et][0] = __builtin_amdgcn_mfma_i32_16x16x64_i8(a0, bf[et][0], acc[tt][et][0], 0, 0, 0);
                acc[tt][et][1] = __builtin_amdgcn_mfma_i32_16x16x64_i8(a0, bf[et][1], acc[tt][et][1], 0, 0, 0);
                acc[tt][et][1] = __builtin_amdgcn_mfma_i32_16x16x64_i8(a1, bf[et][0], acc[tt][et][1], 0, 0, 0);
                acc[tt][et][2] = __builtin_amdgcn_mfma_i32_16x16x64_i8(a0, bf[et][2], acc[tt][et][2], 0, 0, 0);
                acc[tt][et][2] = __builtin_amdgcn_mfma_i32_16x16x64_i8(a1, bf[et][1], acc[tt][et][2], 0, 0, 0);
                acc[tt][et][2] = __builtin_amdgcn_mfma_i32_16x16x64_i8(a2, bf[et][0], acc[tt][et][2], 0, 0, 0);
                acc[tt][et][3] = __builtin_amdgcn_mfma_i32_16x16x64_i8(a0, bf[et][3], acc[tt][et][3], 0, 0, 0);
                acc[tt][et][3] = __builtin_amdgcn_mfma_i32_16x16x64_i8(a1, bf[et][2], acc[tt][et][3], 0, 0, 0);
                acc[tt][et][3] = __builtin_amdgcn_mfma_i32_16x16x64_i8(a2, bf[et][1], acc[tt][et][3], 0, 0, 0);
                acc[tt][et][3] = __builtin_amdgcn_mfma_i32_16x16x64_i8(a3, bf[et][0], acc[tt][et][3], 0, 0, 0);
                acc[tt][et][4] = __builtin_amdgcn_mfma_i32_16x16x64_i8(a0, bf[et][4], acc[tt][et][4], 0, 0, 0);
                acc[tt][et][4] = __builtin_amdgcn_mfma_i32_16x16x64_i8(a1, bf[et][3], acc[tt][et][4], 0, 0, 0);
                acc[tt][et][4] = __builtin_amdgcn_mfma_i32_16x16x64_i8(a2, bf[et][2], acc[tt][et][4], 0, 0, 0);
                acc[tt][et][4] = __builtin_amdgcn_mfma_i32_16x16x64_i8(a3, bf[et][1], acc[tt][et][4], 0, 0, 0);
            }
        }
        if (c + 1 < NCHUNK)
            slice_store_x(Ast + (buf ^ 8192) + swoff, xa, xb);
        __syncthreads();
    }

    // ---- epilogue: exact f64 digit combine, sigmoid + bias -> LDS ----------
    {
        const double w0 = 0x1p-11, w1 = 0x1p-18, w2 = 0x1p-25, w3 = 0x1p-32, w4 = 0x1p-39;
        #pragma unroll
        for (int tt = 0; tt < 2; tt++)
            #pragma unroll
            for (int et = 0; et < 2; et++) {
                const int ecol = wave * 32 + et * 16 + (lane & 15);
                const double bias = (double)Bias[ecol];
                #pragma unroll
                for (int r = 0; r < 4; r++) {
                    const int trow = tt * 16 + (lane >> 4) * 4 + r;
                    const double logit = (double)acc[tt][et][0][r] * w0
                                       + (double)acc[tt][et][1][r] * w1
                                       + (double)acc[tt][et][2][r] * w2
                                       + (double)acc[tt][et][3][r] * w3
                                       + (double)acc[tt][et][4][r] * w4;
                    S[trow * SSTR + ecol] = 1.0 / (1.0 + exp(-logit)) + bias;
                }
            }
    }
    __syncthreads();

    // ---- top-8, one thread per token (stable: lowest index on ties) --------
    if (tid < BT) {
        const int tok = tokBase + tid;
        if (tok < T) {
            double* row = S + tid * SSTR;
            int    cidx[TOPK];
            double csc[TOPK];
            #pragma unroll
            for (int p = 0; p < TOPK; p++) {
                double best = -1e300; int bi = 0;
                for (int e = 0; e < NEXP; e++) {
                    const double v = row[e];
                    if (v > best) { best = v; bi = e; }
                }
                cidx[p] = bi; csc[p] = best; row[bi] = -1e300;
            }
            double sum = 0.0, wts[TOPK];
            #pragma unroll
            for (int p = 0; p < TOPK; p++) {
                const double sg = csc[p] - (double)Bias[cidx[p]];
                wts[p] = sg; sum += sg;
            }
            const double inv = 1.0 / (sum + 1e-20);
            float* oi = Out + (size_t)tok * TOPK;
            float* ow = Out + (size_t)T * TOPK + (size_t)tok * TOPK;
            #pragma unroll
            for (int p = 0; p < TOPK; p++) {
                oi[p] = (float)cidx[p];
                ow[p] = (float)(wts[p] * inv);
            }
        }
    }
}

extern "C" void kernel_launch(void* const* d_in, const int* in_sizes, int n_in,
                              void* d_out, int out_size, void* d_ws, size_t ws_size,
                              hipStream_t stream) {
    const float* X    = (const float*)d_in[0];
    const float* W    = (const float*)d_in[1];
    const float* Bias = (const float*)d_in[2];
    float* Out = (float*)d_out;
    const int T = in_sizes[0] / HIDDEN;
    signed char* P = (signed char*)d_ws;   // 2.62 MB of workspace

    hipLaunchKernelGGL(slice_w_kernel, dim3(NEXP * 512 / 256), dim3(256), 0, stream, W, P);
    hipLaunchKernelGGL(router_kernel, dim3((T + BT - 1) / BT), dim3(256), 0, stream,
                       X, P, Bias, Out, T);
}